// Round 13
// baseline (288.019 us; speedup 1.0000x reference)
//
#include <hip/hip_runtime.h>
#include <hip/hip_fp16.h>
#include <hip/hip_cooperative_groups.h>

namespace cg = cooperative_groups;

// GCN: 3x GCNConv (34->4->4->2) + linear (2->4), N=500K nodes, E=8M edges.
// Round 13 (cleanup at the margins; aggf is within ~10% of the per-CU
// outstanding-miss cap ~0.25-0.3 gather-lines/cy/CU = 64 MSHR / 200cy L2):
// (1) bin dual-buffer: phase A stages (bk<<9|dst_local) in LDS -> phase C
//     never re-reads dst (-32MB); CHUNK 8192, 2x32KB buffers.
// (2) sortb: histogram fused into the staging loop (no second LDS pass).
// (3) aggf: alignment-split dwordx4 nt staging of the edge slice.
// gcn(h)[d] = dinv[d]*(sum_{s->d} g[s] + g[d]) + b,  g[s] = dinv[s]*(h[s]@W).
//
// ws: gcur_pad | bend[NBUK] | dinv[N] | nodeoff[N+1] | ep[NBUK*REGION] |
//     g1h[N+1] half4 | g2h[N+1] half4  (g3h aliases g1h as half2)

#define MAXBUK 1024
#define BUCKET_BITS 9
#define BUCKET 512
#define PAD 16
#define REGION 9216          // fixed entries per bucket; mean 8188, sd ~90 (+11 sigma)

#define BIN_BLK 512
#define BIN_CHUNK 8192

#define SB_BLK 512           // == BUCKET
#define STAGE_MAX REGION

#define AGG_BLK 256
#define SMAX_A 4864          // half-bucket mean 4096, sd ~64 -> +12 sigma

typedef unsigned u32;
typedef int      v4i __attribute__((ext_vector_type(4)));
typedef unsigned v4u __attribute__((ext_vector_type(4)));
typedef float    v2f __attribute__((ext_vector_type(2)));
typedef float    v4f __attribute__((ext_vector_type(4)));

__device__ __forceinline__ u32 ntl_u32(const u32* p) { return __builtin_nontemporal_load(p); }
__device__ __forceinline__ v4i ntl_v4i(const v4i* p) { return __builtin_nontemporal_load(p); }
__device__ __forceinline__ v4u ntl_v4u(const v4u* p) { return __builtin_nontemporal_load(p); }
__device__ __forceinline__ v4f ntl_v4f(const v4f* p) { return __builtin_nontemporal_load(p); }

__device__ __forceinline__ void unp4(uint2 pk, float& x0, float& x1, float& x2, float& x3) {
    __half2 lo = *(__half2*)&pk.x;
    __half2 hi = *(__half2*)&pk.y;
    float2 a = __half22float2(lo);
    float2 c = __half22float2(hi);
    x0 = a.x; x1 = a.y; x2 = c.x; x3 = c.y;
}

// --- kernel 0: init region cursors ---
__global__ void init_kernel(int* __restrict__ gcur, int nbuk) {
    int i = blockIdx.x * 256 + threadIdx.x;
    if (i < nbuk) gcur[i * PAD] = i * REGION;
}

// --- kernel 1: dual-buffer LDS binning; ep = (dst_local << 23) | src ---
__global__ void __launch_bounds__(BIN_BLK, 1)
bin_kernel(const int* __restrict__ src, const int* __restrict__ dst,
           int* __restrict__ gcur, unsigned* __restrict__ ep, int E, int nbuk) {
    __shared__ int hist[MAXBUK];
    __shared__ int lbase[MAXBUK + 1];
    __shared__ int gb[MAXBUK];
    __shared__ int wsum2[8];
    __shared__ int scarry;
    __shared__ unsigned dpk[BIN_CHUNK];    // phase A: (bk<<9)|dst_local
    __shared__ unsigned stage[BIN_CHUNK];  // phase C: bucket-sorted packed edges
    int t = threadIdx.x;
    for (int b = t; b < nbuk; b += BIN_BLK) hist[b] = 0;
    if (t == 0) scarry = 0;
    __syncthreads();
    int e0 = blockIdx.x * BIN_CHUNK;
    int e1 = min(e0 + BIN_CHUNK, E);
    int cn = e1 - e0;
    const v4i* dv = (const v4i*)(dst + e0);
    int n4 = cn >> 2;
    // phase A: histogram + stage packed dst (dst read ONCE)
    for (int i = t; i < n4; i += BIN_BLK) {
        v4i d = ntl_v4i(dv + i);
        int b0 = d.x >> BUCKET_BITS, b1_ = d.y >> BUCKET_BITS;
        int b2_ = d.z >> BUCKET_BITS, b3_ = d.w >> BUCKET_BITS;
        atomicAdd(&hist[b0], 1);
        atomicAdd(&hist[b1_], 1);
        atomicAdd(&hist[b2_], 1);
        atomicAdd(&hist[b3_], 1);
        int p = 4 * i;
        dpk[p + 0] = ((unsigned)b0 << BUCKET_BITS) | (unsigned)(d.x & (BUCKET - 1));
        dpk[p + 1] = ((unsigned)b1_ << BUCKET_BITS) | (unsigned)(d.y & (BUCKET - 1));
        dpk[p + 2] = ((unsigned)b2_ << BUCKET_BITS) | (unsigned)(d.z & (BUCKET - 1));
        dpk[p + 3] = ((unsigned)b3_ << BUCKET_BITS) | (unsigned)(d.w & (BUCKET - 1));
    }
    for (int e = (n4 << 2) + t; e < cn; e += BIN_BLK) {
        int d = dst[e0 + e];
        int bk = d >> BUCKET_BITS;
        atomicAdd(&hist[bk], 1);
        dpk[e] = ((unsigned)bk << BUCKET_BITS) | (unsigned)(d & (BUCKET - 1));
    }
    __syncthreads();
    // phase B: block-local exclusive scan hist -> lbase (shfl wave-scan)
    for (int base = 0; base < nbuk; base += BIN_BLK) {
        int i = base + t;
        int v = (i < nbuk) ? hist[i] : 0;
        int sv2 = v;
#pragma unroll
        for (int off = 1; off < 64; off <<= 1) {
            int n = __shfl_up(sv2, off);
            if ((t & 63) >= off) sv2 += n;
        }
        if ((t & 63) == 63) wsum2[t >> 6] = sv2;
        __syncthreads();
        if (t == 0) {
            int run = scarry;
#pragma unroll
            for (int w2 = 0; w2 < 8; ++w2) { int c = wsum2[w2]; wsum2[w2] = run; run += c; }
            scarry = run;
        }
        __syncthreads();
        if (i < nbuk) lbase[i] = sv2 - v + wsum2[t >> 6];
        __syncthreads();  // protect wsum2/scarry before next chunk
    }
    if (t == 0) lbase[nbuk] = scarry;
    for (int b = t; b < nbuk; b += BIN_BLK) {
        int c = hist[b];
        gb[b] = c ? atomicAdd(&gcur[b * PAD], c) : 0;
        hist[b] = 0;
    }
    __syncthreads();
    // phase C: read src (only) + rank via dpk
    const v4i* sv = (const v4i*)(src + e0);
    for (int i = t; i < n4; i += BIN_BLK) {
        v4i s = ntl_v4i(sv + i);
        int p = 4 * i;
        unsigned v0 = dpk[p], v1 = dpk[p + 1], v2 = dpk[p + 2], v3 = dpk[p + 3];
        int bk; unsigned r;
        bk = (int)(v0 >> BUCKET_BITS); r = (unsigned)atomicAdd(&hist[bk], 1);
        stage[lbase[bk] + r] = ((v0 & (BUCKET - 1u)) << 23) | (unsigned)s.x;
        bk = (int)(v1 >> BUCKET_BITS); r = (unsigned)atomicAdd(&hist[bk], 1);
        stage[lbase[bk] + r] = ((v1 & (BUCKET - 1u)) << 23) | (unsigned)s.y;
        bk = (int)(v2 >> BUCKET_BITS); r = (unsigned)atomicAdd(&hist[bk], 1);
        stage[lbase[bk] + r] = ((v2 & (BUCKET - 1u)) << 23) | (unsigned)s.z;
        bk = (int)(v3 >> BUCKET_BITS); r = (unsigned)atomicAdd(&hist[bk], 1);
        stage[lbase[bk] + r] = ((v3 & (BUCKET - 1u)) << 23) | (unsigned)s.w;
    }
    for (int e = (n4 << 2) + t; e < cn; e += BIN_BLK) {
        unsigned v = dpk[e];
        int bk = (int)(v >> BUCKET_BITS);
        unsigned r = (unsigned)atomicAdd(&hist[bk], 1);
        stage[lbase[bk] + r] = ((v & (BUCKET - 1u)) << 23) | (unsigned)src[e0 + e];
    }
    __syncthreads();
    // phase D: per-bucket coalesced run copy (nt OK: sequential full lines)
    int wid = t >> 6, lane = t & 63;
    for (int b = wid; b < nbuk; b += (BIN_BLK >> 6)) {
        int lo = lbase[b];
        int c = lbase[b + 1] - lo;
        unsigned* dp = ep + gb[b];
        for (int j = lane; j < c; j += 64)
            __builtin_nontemporal_store(stage[lo + j], dp + j);
    }
}

// --- kernel 2: per-bucket counting sort (in place) + nodeoff + bend + dinv
//     + LDS-staged layer-1 transform; histogram fused into staging loop ---
__global__ void __launch_bounds__(SB_BLK)
sortb_kernel(unsigned* __restrict__ ep, const int* __restrict__ gcur,
             const float* __restrict__ x, const float* __restrict__ W1,
             float* __restrict__ dinv, int* __restrict__ nodeoff,
             int* __restrict__ bend, uint2* __restrict__ g1h, int N, int nbuk) {
    __shared__ __align__(16) unsigned stage[STAGE_MAX];
    __shared__ int cnt[BUCKET];
    __shared__ int wsum[8];
    __shared__ float sW[136];
    int t = threadIdx.x, b = blockIdx.x;
    if (t < 136) sW[t] = W1[t];
    cnt[t] = 0;
    int ps = b * REGION;
    int cn = min(gcur[b * PAD] - ps, STAGE_MAX);
    if (t == 0) bend[b] = ps + cn;
    __syncthreads();   // cnt zeroed before fused hist
    const v4u* epv = (const v4u*)(ep + ps);  // ps 16B-aligned (REGION%4==0)
    int n4 = cn >> 2;
    // fused: stage load + histogram from registers
    for (int j = t; j < n4; j += SB_BLK) {
        v4u u = ntl_v4u(epv + j);
        ((v4u*)stage)[j] = u;
        atomicAdd(&cnt[u.x >> 23], 1);
        atomicAdd(&cnt[u.y >> 23], 1);
        atomicAdd(&cnt[u.z >> 23], 1);
        atomicAdd(&cnt[u.w >> 23], 1);
    }
    for (int j = (n4 << 2) + t; j < cn; j += SB_BLK) {
        unsigned u = ntl_u32(ep + ps + j);
        stage[j] = u;
        atomicAdd(&cnt[u >> 23], 1);
    }
    __syncthreads();
    int deg = cnt[t];
    float dv = rsqrtf((float)deg + 1.0f);
    // inclusive wave scan + cross-wave offsets (2 syncs)
    int v = deg;
#pragma unroll
    for (int off = 1; off < 64; off <<= 1) {
        int n = __shfl_up(v, off);
        if ((t & 63) >= off) v += n;
    }
    if ((t & 63) == 63) wsum[t >> 6] = v;
    __syncthreads();
    if (t == 0) {
        int run = 0;
#pragma unroll
        for (int w = 0; w < 8; ++w) { int c = wsum[w]; wsum[w] = run; run += c; }
    }
    __syncthreads();
    int excl = v + wsum[t >> 6] - deg;
    int gbase = b << BUCKET_BITS;
    int nn = min(BUCKET, N - gbase);
    if (t < nn) { nodeoff[gbase + t] = ps + excl; dinv[gbase + t] = dv; }
    cnt[t] = excl;  // scatter cursor
    __syncthreads();
    for (int j = t; j < cn; j += SB_BLK) {
        unsigned u = stage[j];
        int r = atomicAdd(&cnt[u >> 23], 1);
        ep[ps + r] = u & 0x7FFFFFu;  // CACHED store: random scatter, L2 combines
    }
    __syncthreads();           // stage reads + cnt atomics complete
    ((float*)cnt)[t] = dv;     // cnt dead -> park dv for the halves below
    // tf1 with LDS-staged x: two halves of 256 rows, coalesced float4 loads
    float* xs = (float*)stage;  // 256*34 floats = 34816B <= 36864B
    for (int hh = 0; hh < 2; ++hh) {
        int rl = hh << 8;                       // local row base
        int rows = nn - rl; rows = rows < 0 ? 0 : (rows > 256 ? 256 : rows);
        if (rows > 0) {
            if (hh == 1) __syncthreads();       // half-0 compute reads done
            int nfl = rows * 34;
            const float* xsrc = x + (size_t)(gbase + rl) * 34;  // 16B aligned
            int n4f = nfl >> 2;
            for (int j = t; j < n4f; j += SB_BLK)
                ((v4f*)xs)[j] = ntl_v4f((const v4f*)xsrc + j);
            for (int j = (n4f << 2) + t; j < nfl; j += SB_BLK) xs[j] = xsrc[j];
            __syncthreads();
            if (t < rows) {
                float dvv = ((float*)cnt)[rl + t];
                const float* xr = xs + t * 34;  // 2-way bank alias: free
                float o0 = 0.f, o1 = 0.f, o2 = 0.f, o3 = 0.f;
#pragma unroll
                for (int k = 0; k < 17; ++k) {
                    float vx = xr[2 * k], vy = xr[2 * k + 1];
                    o0 = fmaf(vx, sW[(2 * k) * 4 + 0], o0);
                    o1 = fmaf(vx, sW[(2 * k) * 4 + 1], o1);
                    o2 = fmaf(vx, sW[(2 * k) * 4 + 2], o2);
                    o3 = fmaf(vx, sW[(2 * k) * 4 + 3], o3);
                    o0 = fmaf(vy, sW[(2 * k + 1) * 4 + 0], o0);
                    o1 = fmaf(vy, sW[(2 * k + 1) * 4 + 1], o1);
                    o2 = fmaf(vy, sW[(2 * k + 1) * 4 + 2], o2);
                    o3 = fmaf(vy, sW[(2 * k + 1) * 4 + 3], o3);
                }
                __half2 lo = __floats2half2_rn(o0 * dvv, o1 * dvv);
                __half2 hi = __floats2half2_rn(o2 * dvv, o3 * dvv);
                uint2 pk;
                pk.x = *(unsigned*)&lo;
                pk.y = *(unsigned*)&hi;
                g1h[gbase + rl + t] = pk;
            }
        }
    }
}

// --- agg phase bodies (shared by fused + fallback kernels) ---
#define ACC4(Q) { float t0,t1,t2,t3; unp4(Q,t0,t1,t2,t3); a0+=t0; a1+=t1; a2+=t2; a3+=t3; }

__device__ __forceinline__ void phase1(int i, int lo, int hi, int cs, int s,
        const unsigned* se, const unsigned* __restrict__ esrc,
        const uint2* __restrict__ g1h, float dv,
        const float* __restrict__ b1, const float* __restrict__ W2,
        uint2* __restrict__ g2h) {
    float a0, a1, a2, a3;
    unp4(g1h[i], a0, a1, a2, a3);  // self loop
    int hi2 = min(hi, cs);
    int j = lo;
    for (; j + 8 <= hi2; j += 8) {
        unsigned s0 = se[j], s1 = se[j+1], s2 = se[j+2], s3 = se[j+3];
        unsigned s4 = se[j+4], s5 = se[j+5], s6 = se[j+6], s7 = se[j+7];
        uint2 q0 = g1h[s0], q1 = g1h[s1], q2 = g1h[s2], q3 = g1h[s3];
        uint2 q4 = g1h[s4], q5 = g1h[s5], q6 = g1h[s6], q7 = g1h[s7];
        ACC4(q0) ACC4(q1) ACC4(q2) ACC4(q3) ACC4(q4) ACC4(q5) ACC4(q6) ACC4(q7)
    }
    for (; j + 4 <= hi2; j += 4) {
        unsigned s0 = se[j], s1 = se[j+1], s2 = se[j+2], s3 = se[j+3];
        uint2 q0 = g1h[s0], q1 = g1h[s1], q2 = g1h[s2], q3 = g1h[s3];
        ACC4(q0) ACC4(q1) ACC4(q2) ACC4(q3)
    }
    for (; j < hi2; ++j) ACC4(g1h[se[j]])
    for (; j < hi; ++j) ACC4(g1h[ntl_u32(esrc + s + j)])  // overflow fallback
    float h0 = fmaxf(fmaf(a0, dv, b1[0]), 0.f);
    float h1 = fmaxf(fmaf(a1, dv, b1[1]), 0.f);
    float h2 = fmaxf(fmaf(a2, dv, b1[2]), 0.f);
    float h3 = fmaxf(fmaf(a3, dv, b1[3]), 0.f);
    float o0 = dv * (h0 * W2[0] + h1 * W2[4] + h2 * W2[8] + h3 * W2[12]);
    float o1 = dv * (h0 * W2[1] + h1 * W2[5] + h2 * W2[9] + h3 * W2[13]);
    float o2 = dv * (h0 * W2[2] + h1 * W2[6] + h2 * W2[10] + h3 * W2[14]);
    float o3 = dv * (h0 * W2[3] + h1 * W2[7] + h2 * W2[11] + h3 * W2[15]);
    __half2 lo2 = __floats2half2_rn(o0, o1);
    __half2 hi3 = __floats2half2_rn(o2, o3);
    uint2 pk;
    pk.x = *(unsigned*)&lo2;
    pk.y = *(unsigned*)&hi3;
    g2h[i] = pk;
}

__device__ __forceinline__ void phase2(int i, int lo, int hi, int cs, int s,
        const unsigned* se, const unsigned* __restrict__ esrc,
        const uint2* __restrict__ g2h, float dv,
        const float* __restrict__ b2, const float* __restrict__ W3,
        unsigned* __restrict__ g3h) {
    float a0, a1, a2, a3;
    unp4(g2h[i], a0, a1, a2, a3);
    int hi2 = min(hi, cs);
    int j = lo;
    for (; j + 8 <= hi2; j += 8) {
        unsigned s0 = se[j], s1 = se[j+1], s2 = se[j+2], s3 = se[j+3];
        unsigned s4 = se[j+4], s5 = se[j+5], s6 = se[j+6], s7 = se[j+7];
        uint2 q0 = g2h[s0], q1 = g2h[s1], q2 = g2h[s2], q3 = g2h[s3];
        uint2 q4 = g2h[s4], q5 = g2h[s5], q6 = g2h[s6], q7 = g2h[s7];
        ACC4(q0) ACC4(q1) ACC4(q2) ACC4(q3) ACC4(q4) ACC4(q5) ACC4(q6) ACC4(q7)
    }
    for (; j + 4 <= hi2; j += 4) {
        unsigned s0 = se[j], s1 = se[j+1], s2 = se[j+2], s3 = se[j+3];
        uint2 q0 = g2h[s0], q1 = g2h[s1], q2 = g2h[s2], q3 = g2h[s3];
        ACC4(q0) ACC4(q1) ACC4(q2) ACC4(q3)
    }
    for (; j < hi2; ++j) ACC4(g2h[se[j]])
    for (; j < hi; ++j) ACC4(g2h[ntl_u32(esrc + s + j)])
    float h0 = fmaxf(fmaf(a0, dv, b2[0]), 0.f);
    float h1 = fmaxf(fmaf(a1, dv, b2[1]), 0.f);
    float h2 = fmaxf(fmaf(a2, dv, b2[2]), 0.f);
    float h3 = fmaxf(fmaf(a3, dv, b2[3]), 0.f);
    float o0 = dv * (h0 * W3[0] + h1 * W3[2] + h2 * W3[4] + h3 * W3[6]);
    float o1 = dv * (h0 * W3[1] + h1 * W3[3] + h2 * W3[5] + h3 * W3[7]);
    __half2 oo = __floats2half2_rn(o0, o1);
    g3h[i] = *(unsigned*)&oo;
}

__device__ __forceinline__ void phase3(int i, int lo, int hi, int cs, int s,
        const unsigned* se, const unsigned* __restrict__ esrc,
        const unsigned* __restrict__ g3h, float dv,
        const float* __restrict__ b3, const float* __restrict__ Wl,
        const float* __restrict__ bl, float* __restrict__ out, int N) {
    unsigned pk = g3h[i];
    float2 v = __half22float2(*(__half2*)&pk);
    float ax = v.x, ay = v.y;
    int hi2 = min(hi, cs);
    int j = lo;
    for (; j + 8 <= hi2; j += 8) {
        unsigned q0 = g3h[se[j]],   q1 = g3h[se[j+1]], q2 = g3h[se[j+2]], q3 = g3h[se[j+3]];
        unsigned q4 = g3h[se[j+4]], q5 = g3h[se[j+5]], q6 = g3h[se[j+6]], q7 = g3h[se[j+7]];
        float2 v0 = __half22float2(*(__half2*)&q0);
        float2 v1 = __half22float2(*(__half2*)&q1);
        float2 v2 = __half22float2(*(__half2*)&q2);
        float2 v3 = __half22float2(*(__half2*)&q3);
        float2 v4 = __half22float2(*(__half2*)&q4);
        float2 v5 = __half22float2(*(__half2*)&q5);
        float2 v6 = __half22float2(*(__half2*)&q6);
        float2 v7 = __half22float2(*(__half2*)&q7);
        ax += (v0.x + v1.x + v2.x + v3.x) + (v4.x + v5.x + v6.x + v7.x);
        ay += (v0.y + v1.y + v2.y + v3.y) + (v4.y + v5.y + v6.y + v7.y);
    }
    for (; j + 4 <= hi2; j += 4) {
        unsigned q0 = g3h[se[j]], q1 = g3h[se[j+1]], q2 = g3h[se[j+2]], q3 = g3h[se[j+3]];
        float2 v0 = __half22float2(*(__half2*)&q0);
        float2 v1 = __half22float2(*(__half2*)&q1);
        float2 v2 = __half22float2(*(__half2*)&q2);
        float2 v3 = __half22float2(*(__half2*)&q3);
        ax += v0.x + v1.x + v2.x + v3.x;
        ay += v0.y + v1.y + v2.y + v3.y;
    }
    for (; j < hi2; ++j) {
        unsigned q = g3h[se[j]];
        float2 w = __half22float2(*(__half2*)&q);
        ax += w.x; ay += w.y;
    }
    for (; j < hi; ++j) {
        unsigned q = g3h[ntl_u32(esrc + s + j)];
        float2 w = __half22float2(*(__half2*)&q);
        ax += w.x; ay += w.y;
    }
    float h0 = fmaxf(fmaf(ax, dv, b3[0]), 0.f);
    float h1 = fmaxf(fmaf(ay, dv, b3[1]), 0.f);
    v4f oo;
    oo.x = fmaf(h0, Wl[0], fmaf(h1, Wl[4], bl[0]));
    oo.y = fmaf(h0, Wl[1], fmaf(h1, Wl[5], bl[1]));
    oo.z = fmaf(h0, Wl[2], fmaf(h1, Wl[6], bl[2]));
    oo.w = fmaf(h0, Wl[3], fmaf(h1, Wl[7], bl[3]));
    __builtin_nontemporal_store(oo, (v4f*)out + i);
    v2f h; h.x = h0; h.y = h1;
    __builtin_nontemporal_store(h, (v2f*)(out + (size_t)4 * N) + i);
}

// common per-block geometry
struct BlkGeo { int s, cs, lo, hi; bool act; int i; float dv; };

__device__ __forceinline__ BlkGeo geo(const int* __restrict__ nodeoff,
                                      const int* __restrict__ bend,
                                      const float* __restrict__ dinv, int N) {
    BlkGeo g;
    int t = threadIdx.x, blk = blockIdx.x, buk = blk >> 1;
    int gbase = (buk << BUCKET_BITS) + ((blk & 1) << 8);
    int nn = min(256, N - gbase);
    g.i = gbase + t;
    g.act = (nn > 0) && (t < nn);
    g.s = 0; g.cs = 0; g.lo = 0; g.hi = 0; g.dv = 0.f;
    if (nn > 0) {
        g.s = nodeoff[gbase];
        int nbn = min(512, N - (buk << BUCKET_BITS));
        bool lasthalf = (blk & 1) ? true : (nbn <= 256);
        int e = lasthalf ? bend[buk] : nodeoff[gbase + 256];
        g.cs = min(e - g.s, SMAX_A);
        if (g.act) {
            bool lastnode = lasthalf && (t == nn - 1);
            g.lo = nodeoff[g.i] - g.s;
            g.hi = (lastnode ? bend[buk] : nodeoff[g.i + 1]) - g.s;
            g.dv = dinv[g.i];
        }
    }
    return g;
}

// alignment-split vectorized staging of the edge slice into LDS
__device__ __forceinline__ void stage_se(unsigned* se, const unsigned* __restrict__ esrc,
                                         int s, int cs, int t) {
    int head = (4 - (s & 3)) & 3;
    if (head > cs) head = cs;
    for (int j = t; j < head; j += AGG_BLK) se[j] = ntl_u32(esrc + s + j);
    int nv = (cs - head) >> 2;
    const v4u* evp = (const v4u*)(esrc + s + head);   // 16B aligned
    for (int j = t; j < nv; j += AGG_BLK) {
        v4u u = ntl_v4u(evp + j);
        int p = head + 4 * j;
        se[p] = u.x; se[p + 1] = u.y; se[p + 2] = u.z; se[p + 3] = u.w;
    }
    for (int j = head + (nv << 2) + t; j < cs; j += AGG_BLK) se[j] = ntl_u32(esrc + s + j);
}

// --- kernel 3 (cooperative): all three agg layers, edge slice staged once ---
__global__ void __launch_bounds__(AGG_BLK, 8)
aggf_kernel(const unsigned* __restrict__ esrc, const int* __restrict__ nodeoff,
            const int* __restrict__ bend, const float* __restrict__ dinv,
            uint2* __restrict__ g1h, uint2* __restrict__ g2h,
            const float* __restrict__ b1, const float* __restrict__ W2,
            const float* __restrict__ b2, const float* __restrict__ W3,
            const float* __restrict__ b3, const float* __restrict__ Wl,
            const float* __restrict__ bl, float* __restrict__ out, int N) {
    cg::grid_group gg = cg::this_grid();
    __shared__ unsigned se[SMAX_A];
    BlkGeo g = geo(nodeoff, bend, dinv, N);
    int t = threadIdx.x;
    stage_se(se, esrc, g.s, g.cs, t);
    __syncthreads();
    if (g.act) phase1(g.i, g.lo, g.hi, g.cs, g.s, se, esrc, g1h, g.dv, b1, W2, g2h);
    gg.sync();
    unsigned* g3h = (unsigned*)g1h;  // g1 dead after phase1
    if (g.act) phase2(g.i, g.lo, g.hi, g.cs, g.s, se, esrc, g2h, g.dv, b2, W3, g3h);
    gg.sync();
    if (g.act) phase3(g.i, g.lo, g.hi, g.cs, g.s, se, esrc, g3h, g.dv, b3, Wl, bl, out, N);
}

// --- fallback: one phase per launch (if cooperative capacity insufficient) ---
template <int P>
__global__ void __launch_bounds__(AGG_BLK)
aggp_kernel(const unsigned* __restrict__ esrc, const int* __restrict__ nodeoff,
            const int* __restrict__ bend, const float* __restrict__ dinv,
            uint2* __restrict__ g1h, uint2* __restrict__ g2h,
            const float* __restrict__ b1, const float* __restrict__ W2,
            const float* __restrict__ b2, const float* __restrict__ W3,
            const float* __restrict__ b3, const float* __restrict__ Wl,
            const float* __restrict__ bl, float* __restrict__ out, int N) {
    __shared__ unsigned se[SMAX_A];
    BlkGeo g = geo(nodeoff, bend, dinv, N);
    int t = threadIdx.x;
    stage_se(se, esrc, g.s, g.cs, t);
    __syncthreads();
    unsigned* g3h = (unsigned*)g1h;
    if (g.act) {
        if (P == 1) phase1(g.i, g.lo, g.hi, g.cs, g.s, se, esrc, g1h, g.dv, b1, W2, g2h);
        if (P == 2) phase2(g.i, g.lo, g.hi, g.cs, g.s, se, esrc, g2h, g.dv, b2, W3, g3h);
        if (P == 3) phase3(g.i, g.lo, g.hi, g.cs, g.s, se, esrc, g3h, g.dv, b3, Wl, bl, out, N);
    }
}

extern "C" void kernel_launch(void* const* d_in, const int* in_sizes, int n_in,
                              void* d_out, int out_size, void* d_ws, size_t ws_size,
                              hipStream_t stream) {
    const float* x  = (const float*)d_in[0];
    const int*   ei = (const int*)d_in[1];
    const float* W1 = (const float*)d_in[2];
    const float* b1 = (const float*)d_in[3];
    const float* W2 = (const float*)d_in[4];
    const float* b2 = (const float*)d_in[5];
    const float* W3 = (const float*)d_in[6];
    const float* b3 = (const float*)d_in[7];
    const float* Wl = (const float*)d_in[8];
    const float* bl = (const float*)d_in[9];
    float* out = (float*)d_out;

    int N = in_sizes[0] / 34;
    const int E = in_sizes[1] / 2;
    const int* src = ei;
    const int* dst = ei + E;
    const int NBUK = (N + BUCKET - 1) >> BUCKET_BITS;

    auto al16 = [](size_t v) { return (v + 15) & ~(size_t)15; };
    char* w = (char*)d_ws;
    size_t off = 0;
    int*      gcur    = (int*)(w + off);      off += al16((size_t)NBUK * PAD * 4);
    int*      bend    = (int*)(w + off);      off += al16((size_t)NBUK * 4);
    float*    dinv    = (float*)(w + off);    off += al16((size_t)N * 4);
    int*      nodeoff = (int*)(w + off);      off += al16((size_t)(N + 1) * 4);
    unsigned* ep      = (unsigned*)(w + off); off += al16((size_t)NBUK * REGION * 4);
    uint2*    g1h     = (uint2*)(w + off);    off += al16((size_t)(N + 1) * 8);
    uint2*    g2h     = (uint2*)(w + off);

    const int nb_bin = (E + BIN_CHUNK - 1) / BIN_CHUNK;
    const int nb_agg = 2 * NBUK;

    init_kernel<<<(NBUK + 255) / 256, 256, 0, stream>>>(gcur, NBUK);
    bin_kernel<<<nb_bin, BIN_BLK, 0, stream>>>(src, dst, gcur, ep, E, NBUK);
    sortb_kernel<<<NBUK, SB_BLK, 0, stream>>>(ep, gcur, x, W1, dinv, nodeoff, bend, g1h, N, NBUK);

    // cooperative fused agg if all blocks fit concurrently, else 3 launches
    int blocksPerCU = 0, ncu = 0, dev = 0;
    hipGetDevice(&dev);
    hipDeviceGetAttribute(&ncu, hipDeviceAttributeMultiprocessorCount, dev);
    hipOccupancyMaxActiveBlocksPerMultiprocessor(&blocksPerCU, (const void*)aggf_kernel, AGG_BLK, 0);
    if (blocksPerCU * ncu >= nb_agg) {
        void* args[] = {(void*)&ep, (void*)&nodeoff, (void*)&bend, (void*)&dinv,
                        (void*)&g1h, (void*)&g2h, (void*)&b1, (void*)&W2,
                        (void*)&b2, (void*)&W3, (void*)&b3, (void*)&Wl,
                        (void*)&bl, (void*)&out, (void*)&N};
        hipLaunchCooperativeKernel((const void*)aggf_kernel, dim3(nb_agg), dim3(AGG_BLK),
                                   args, 0, stream);
    } else {
        aggp_kernel<1><<<nb_agg, AGG_BLK, 0, stream>>>(ep, nodeoff, bend, dinv, g1h, g2h,
                                                       b1, W2, b2, W3, b3, Wl, bl, out, N);
        aggp_kernel<2><<<nb_agg, AGG_BLK, 0, stream>>>(ep, nodeoff, bend, dinv, g1h, g2h,
                                                       b1, W2, b2, W3, b3, Wl, bl, out, N);
        aggp_kernel<3><<<nb_agg, AGG_BLK, 0, stream>>>(ep, nodeoff, bend, dinv, g1h, g2h,
                                                       b1, W2, b2, W3, b3, Wl, bl, out, N);
    }
}

// Round 14
// 264.628 us; speedup vs baseline: 1.0884x; 1.0884x over previous
//
#include <hip/hip_runtime.h>
#include <hip/hip_fp16.h>
#include <hip/hip_cooperative_groups.h>

namespace cg = cooperative_groups;

// GCN: 3x GCNConv (34->4->4->2) + linear (2->4), N=500K nodes, E=8M edges.
// Round 14: surgical revert of R13's two regressions to the R12 best-known:
// (a) bin back to CHUNK=16384 single-buffer (R13's dual-buffer halved CHUNK,
//     doubling bin's per-block fixed costs: hist-zero/scan/reserve of 1024
//     buckets x2 cost more than the 32MB dst re-read saved);
// (b) aggf staging back to stride-1 scalar loop (R13's "vectorized" LDS
//     write was stride-16B/lane -> 8-way ds_write conflict, +39% on
//     SQ_LDS_BANK_CONFLICT). Keeps R13's sortb fused histogram (one less
//     LDS pass, not implicated in the regression).
// aggf is at the per-CU outstanding-miss cap for 24M random L2 gathers
// (invariant across fp32/fp16/nt/4-wide/8-wide traffic knobs).
// gcn(h)[d] = dinv[d]*(sum_{s->d} g[s] + g[d]) + b,  g[s] = dinv[s]*(h[s]@W).
//
// ws: gcur_pad | bend[NBUK] | dinv[N] | nodeoff[N+1] | ep[NBUK*REGION] |
//     g1h[N+1] half4 | g2h[N+1] half4  (g3h aliases g1h as half2)

#define MAXBUK 1024
#define BUCKET_BITS 9
#define BUCKET 512
#define PAD 16
#define REGION 9216          // fixed entries per bucket; mean 8188, sd ~90 (+11 sigma)

#define BIN_BLK 512
#define BIN_CHUNK 16384

#define SB_BLK 512           // == BUCKET
#define STAGE_MAX REGION

#define AGG_BLK 256
#define SMAX_A 4864          // half-bucket mean 4096, sd ~64 -> +12 sigma

typedef unsigned u32;
typedef int      v4i __attribute__((ext_vector_type(4)));
typedef unsigned v4u __attribute__((ext_vector_type(4)));
typedef float    v2f __attribute__((ext_vector_type(2)));
typedef float    v4f __attribute__((ext_vector_type(4)));

__device__ __forceinline__ u32 ntl_u32(const u32* p) { return __builtin_nontemporal_load(p); }
__device__ __forceinline__ v4i ntl_v4i(const v4i* p) { return __builtin_nontemporal_load(p); }
__device__ __forceinline__ v4u ntl_v4u(const v4u* p) { return __builtin_nontemporal_load(p); }
__device__ __forceinline__ v4f ntl_v4f(const v4f* p) { return __builtin_nontemporal_load(p); }

__device__ __forceinline__ void unp4(uint2 pk, float& x0, float& x1, float& x2, float& x3) {
    __half2 lo = *(__half2*)&pk.x;
    __half2 hi = *(__half2*)&pk.y;
    float2 a = __half22float2(lo);
    float2 c = __half22float2(hi);
    x0 = a.x; x1 = a.y; x2 = c.x; x3 = c.y;
}

// --- kernel 0: init region cursors ---
__global__ void init_kernel(int* __restrict__ gcur, int nbuk) {
    int i = blockIdx.x * 256 + threadIdx.x;
    if (i < nbuk) gcur[i * PAD] = i * REGION;
}

// --- kernel 1: LDS-staged binning; ep = (dst_local << 23) | src ---
__global__ void __launch_bounds__(BIN_BLK, 1)
bin_kernel(const int* __restrict__ src, const int* __restrict__ dst,
           int* __restrict__ gcur, unsigned* __restrict__ ep, int E, int nbuk) {
    __shared__ int hist[MAXBUK];
    __shared__ int lbase[MAXBUK + 1];
    __shared__ int gb[MAXBUK];
    __shared__ int wsum2[8];
    __shared__ int scarry;
    __shared__ unsigned stage[BIN_CHUNK];
    int t = threadIdx.x;
    for (int b = t; b < nbuk; b += BIN_BLK) hist[b] = 0;
    if (t == 0) scarry = 0;
    __syncthreads();
    int e0 = blockIdx.x * BIN_CHUNK;
    int e1 = min(e0 + BIN_CHUNK, E);
    int cn = e1 - e0;
    const v4i* dv = (const v4i*)(dst + e0);
    const v4i* sv = (const v4i*)(src + e0);
    int n4 = cn >> 2;
    // phase A: histogram
    for (int i = t; i < n4; i += BIN_BLK) {
        v4i d = dv[i];
        atomicAdd(&hist[d.x >> BUCKET_BITS], 1);
        atomicAdd(&hist[d.y >> BUCKET_BITS], 1);
        atomicAdd(&hist[d.z >> BUCKET_BITS], 1);
        atomicAdd(&hist[d.w >> BUCKET_BITS], 1);
    }
    for (int e = (n4 << 2) + t; e < cn; e += BIN_BLK)
        atomicAdd(&hist[dst[e0 + e] >> BUCKET_BITS], 1);
    __syncthreads();
    // phase B: block-local exclusive scan hist -> lbase (shfl wave-scan)
    for (int base = 0; base < nbuk; base += BIN_BLK) {
        int i = base + t;
        int v = (i < nbuk) ? hist[i] : 0;
        int sv2 = v;
#pragma unroll
        for (int off = 1; off < 64; off <<= 1) {
            int n = __shfl_up(sv2, off);
            if ((t & 63) >= off) sv2 += n;
        }
        if ((t & 63) == 63) wsum2[t >> 6] = sv2;
        __syncthreads();
        if (t == 0) {
            int run = scarry;
#pragma unroll
            for (int w2 = 0; w2 < 8; ++w2) { int c = wsum2[w2]; wsum2[w2] = run; run += c; }
            scarry = run;
        }
        __syncthreads();
        if (i < nbuk) lbase[i] = sv2 - v + wsum2[t >> 6];
        __syncthreads();  // protect wsum2/scarry before next chunk
    }
    if (t == 0) lbase[nbuk] = scarry;
    for (int b = t; b < nbuk; b += BIN_BLK) {
        int c = hist[b];
        gb[b] = c ? atomicAdd(&gcur[b * PAD], c) : 0;
        hist[b] = 0;
    }
    __syncthreads();
    // phase C: rank + stage
    for (int i = t; i < n4; i += BIN_BLK) {
        v4i d = ntl_v4i(dv + i);
        v4i s = ntl_v4i(sv + i);
        int bk, r;
        bk = d.x >> BUCKET_BITS; r = atomicAdd(&hist[bk], 1);
        stage[lbase[bk] + r] = ((unsigned)(d.x & (BUCKET - 1)) << 23) | (unsigned)s.x;
        bk = d.y >> BUCKET_BITS; r = atomicAdd(&hist[bk], 1);
        stage[lbase[bk] + r] = ((unsigned)(d.y & (BUCKET - 1)) << 23) | (unsigned)s.y;
        bk = d.z >> BUCKET_BITS; r = atomicAdd(&hist[bk], 1);
        stage[lbase[bk] + r] = ((unsigned)(d.z & (BUCKET - 1)) << 23) | (unsigned)s.z;
        bk = d.w >> BUCKET_BITS; r = atomicAdd(&hist[bk], 1);
        stage[lbase[bk] + r] = ((unsigned)(d.w & (BUCKET - 1)) << 23) | (unsigned)s.w;
    }
    for (int e = (n4 << 2) + t; e < cn; e += BIN_BLK) {
        int d = dst[e0 + e];
        int bk = d >> BUCKET_BITS;
        int r = atomicAdd(&hist[bk], 1);
        stage[lbase[bk] + r] = ((unsigned)(d & (BUCKET - 1)) << 23) | (unsigned)src[e0 + e];
    }
    __syncthreads();
    // phase D: per-bucket coalesced run copy (nt OK: sequential full lines)
    int wid = t >> 6, lane = t & 63;
    for (int b = wid; b < nbuk; b += (BIN_BLK >> 6)) {
        int lo = lbase[b];
        int c = lbase[b + 1] - lo;
        unsigned* dp = ep + gb[b];
        for (int j = lane; j < c; j += 64)
            __builtin_nontemporal_store(stage[lo + j], dp + j);
    }
}

// --- kernel 2: per-bucket counting sort (in place) + nodeoff + bend + dinv
//     + LDS-staged layer-1 transform; histogram fused into staging loop ---
__global__ void __launch_bounds__(SB_BLK)
sortb_kernel(unsigned* __restrict__ ep, const int* __restrict__ gcur,
             const float* __restrict__ x, const float* __restrict__ W1,
             float* __restrict__ dinv, int* __restrict__ nodeoff,
             int* __restrict__ bend, uint2* __restrict__ g1h, int N, int nbuk) {
    __shared__ __align__(16) unsigned stage[STAGE_MAX];
    __shared__ int cnt[BUCKET];
    __shared__ int wsum[8];
    __shared__ float sW[136];
    int t = threadIdx.x, b = blockIdx.x;
    if (t < 136) sW[t] = W1[t];
    cnt[t] = 0;
    int ps = b * REGION;
    int cn = min(gcur[b * PAD] - ps, STAGE_MAX);
    if (t == 0) bend[b] = ps + cn;
    __syncthreads();   // cnt zeroed before fused hist
    const v4u* epv = (const v4u*)(ep + ps);  // ps 16B-aligned (REGION%4==0)
    int n4 = cn >> 2;
    // fused: stage load + histogram from registers
    for (int j = t; j < n4; j += SB_BLK) {
        v4u u = ntl_v4u(epv + j);
        ((v4u*)stage)[j] = u;
        atomicAdd(&cnt[u.x >> 23], 1);
        atomicAdd(&cnt[u.y >> 23], 1);
        atomicAdd(&cnt[u.z >> 23], 1);
        atomicAdd(&cnt[u.w >> 23], 1);
    }
    for (int j = (n4 << 2) + t; j < cn; j += SB_BLK) {
        unsigned u = ntl_u32(ep + ps + j);
        stage[j] = u;
        atomicAdd(&cnt[u >> 23], 1);
    }
    __syncthreads();
    int deg = cnt[t];
    float dv = rsqrtf((float)deg + 1.0f);
    // inclusive wave scan + cross-wave offsets (2 syncs)
    int v = deg;
#pragma unroll
    for (int off = 1; off < 64; off <<= 1) {
        int n = __shfl_up(v, off);
        if ((t & 63) >= off) v += n;
    }
    if ((t & 63) == 63) wsum[t >> 6] = v;
    __syncthreads();
    if (t == 0) {
        int run = 0;
#pragma unroll
        for (int w = 0; w < 8; ++w) { int c = wsum[w]; wsum[w] = run; run += c; }
    }
    __syncthreads();
    int excl = v + wsum[t >> 6] - deg;
    int gbase = b << BUCKET_BITS;
    int nn = min(BUCKET, N - gbase);
    if (t < nn) { nodeoff[gbase + t] = ps + excl; dinv[gbase + t] = dv; }
    cnt[t] = excl;  // scatter cursor
    __syncthreads();
    for (int j = t; j < cn; j += SB_BLK) {
        unsigned u = stage[j];
        int r = atomicAdd(&cnt[u >> 23], 1);
        ep[ps + r] = u & 0x7FFFFFu;  // CACHED store: random scatter, L2 combines
    }
    __syncthreads();           // stage reads + cnt atomics complete
    ((float*)cnt)[t] = dv;     // cnt dead -> park dv for the halves below
    // tf1 with LDS-staged x: two halves of 256 rows, coalesced float4 loads
    float* xs = (float*)stage;  // 256*34 floats = 34816B <= 36864B
    for (int hh = 0; hh < 2; ++hh) {
        int rl = hh << 8;                       // local row base
        int rows = nn - rl; rows = rows < 0 ? 0 : (rows > 256 ? 256 : rows);
        if (rows > 0) {
            if (hh == 1) __syncthreads();       // half-0 compute reads done
            int nfl = rows * 34;
            const float* xsrc = x + (size_t)(gbase + rl) * 34;  // 16B aligned
            int n4f = nfl >> 2;
            for (int j = t; j < n4f; j += SB_BLK)
                ((v4f*)xs)[j] = ntl_v4f((const v4f*)xsrc + j);
            for (int j = (n4f << 2) + t; j < nfl; j += SB_BLK) xs[j] = xsrc[j];
            __syncthreads();
            if (t < rows) {
                float dvv = ((float*)cnt)[rl + t];
                const float* xr = xs + t * 34;  // 2-way bank alias: free
                float o0 = 0.f, o1 = 0.f, o2 = 0.f, o3 = 0.f;
#pragma unroll
                for (int k = 0; k < 17; ++k) {
                    float vx = xr[2 * k], vy = xr[2 * k + 1];
                    o0 = fmaf(vx, sW[(2 * k) * 4 + 0], o0);
                    o1 = fmaf(vx, sW[(2 * k) * 4 + 1], o1);
                    o2 = fmaf(vx, sW[(2 * k) * 4 + 2], o2);
                    o3 = fmaf(vx, sW[(2 * k) * 4 + 3], o3);
                    o0 = fmaf(vy, sW[(2 * k + 1) * 4 + 0], o0);
                    o1 = fmaf(vy, sW[(2 * k + 1) * 4 + 1], o1);
                    o2 = fmaf(vy, sW[(2 * k + 1) * 4 + 2], o2);
                    o3 = fmaf(vy, sW[(2 * k + 1) * 4 + 3], o3);
                }
                __half2 lo = __floats2half2_rn(o0 * dvv, o1 * dvv);
                __half2 hi = __floats2half2_rn(o2 * dvv, o3 * dvv);
                uint2 pk;
                pk.x = *(unsigned*)&lo;
                pk.y = *(unsigned*)&hi;
                g1h[gbase + rl + t] = pk;
            }
        }
    }
}

// --- agg phase bodies (shared by fused + fallback kernels) ---
#define ACC4(Q) { float t0,t1,t2,t3; unp4(Q,t0,t1,t2,t3); a0+=t0; a1+=t1; a2+=t2; a3+=t3; }

__device__ __forceinline__ void phase1(int i, int lo, int hi, int cs, int s,
        const unsigned* se, const unsigned* __restrict__ esrc,
        const uint2* __restrict__ g1h, float dv,
        const float* __restrict__ b1, const float* __restrict__ W2,
        uint2* __restrict__ g2h) {
    float a0, a1, a2, a3;
    unp4(g1h[i], a0, a1, a2, a3);  // self loop
    int hi2 = min(hi, cs);
    int j = lo;
    for (; j + 8 <= hi2; j += 8) {
        unsigned s0 = se[j], s1 = se[j+1], s2 = se[j+2], s3 = se[j+3];
        unsigned s4 = se[j+4], s5 = se[j+5], s6 = se[j+6], s7 = se[j+7];
        uint2 q0 = g1h[s0], q1 = g1h[s1], q2 = g1h[s2], q3 = g1h[s3];
        uint2 q4 = g1h[s4], q5 = g1h[s5], q6 = g1h[s6], q7 = g1h[s7];
        ACC4(q0) ACC4(q1) ACC4(q2) ACC4(q3) ACC4(q4) ACC4(q5) ACC4(q6) ACC4(q7)
    }
    for (; j + 4 <= hi2; j += 4) {
        unsigned s0 = se[j], s1 = se[j+1], s2 = se[j+2], s3 = se[j+3];
        uint2 q0 = g1h[s0], q1 = g1h[s1], q2 = g1h[s2], q3 = g1h[s3];
        ACC4(q0) ACC4(q1) ACC4(q2) ACC4(q3)
    }
    for (; j < hi2; ++j) ACC4(g1h[se[j]])
    for (; j < hi; ++j) ACC4(g1h[ntl_u32(esrc + s + j)])  // overflow fallback
    float h0 = fmaxf(fmaf(a0, dv, b1[0]), 0.f);
    float h1 = fmaxf(fmaf(a1, dv, b1[1]), 0.f);
    float h2 = fmaxf(fmaf(a2, dv, b1[2]), 0.f);
    float h3 = fmaxf(fmaf(a3, dv, b1[3]), 0.f);
    float o0 = dv * (h0 * W2[0] + h1 * W2[4] + h2 * W2[8] + h3 * W2[12]);
    float o1 = dv * (h0 * W2[1] + h1 * W2[5] + h2 * W2[9] + h3 * W2[13]);
    float o2 = dv * (h0 * W2[2] + h1 * W2[6] + h2 * W2[10] + h3 * W2[14]);
    float o3 = dv * (h0 * W2[3] + h1 * W2[7] + h2 * W2[11] + h3 * W2[15]);
    __half2 lo2 = __floats2half2_rn(o0, o1);
    __half2 hi3 = __floats2half2_rn(o2, o3);
    uint2 pk;
    pk.x = *(unsigned*)&lo2;
    pk.y = *(unsigned*)&hi3;
    g2h[i] = pk;
}

__device__ __forceinline__ void phase2(int i, int lo, int hi, int cs, int s,
        const unsigned* se, const unsigned* __restrict__ esrc,
        const uint2* __restrict__ g2h, float dv,
        const float* __restrict__ b2, const float* __restrict__ W3,
        unsigned* __restrict__ g3h) {
    float a0, a1, a2, a3;
    unp4(g2h[i], a0, a1, a2, a3);
    int hi2 = min(hi, cs);
    int j = lo;
    for (; j + 8 <= hi2; j += 8) {
        unsigned s0 = se[j], s1 = se[j+1], s2 = se[j+2], s3 = se[j+3];
        unsigned s4 = se[j+4], s5 = se[j+5], s6 = se[j+6], s7 = se[j+7];
        uint2 q0 = g2h[s0], q1 = g2h[s1], q2 = g2h[s2], q3 = g2h[s3];
        uint2 q4 = g2h[s4], q5 = g2h[s5], q6 = g2h[s6], q7 = g2h[s7];
        ACC4(q0) ACC4(q1) ACC4(q2) ACC4(q3) ACC4(q4) ACC4(q5) ACC4(q6) ACC4(q7)
    }
    for (; j + 4 <= hi2; j += 4) {
        unsigned s0 = se[j], s1 = se[j+1], s2 = se[j+2], s3 = se[j+3];
        uint2 q0 = g2h[s0], q1 = g2h[s1], q2 = g2h[s2], q3 = g2h[s3];
        ACC4(q0) ACC4(q1) ACC4(q2) ACC4(q3)
    }
    for (; j < hi2; ++j) ACC4(g2h[se[j]])
    for (; j < hi; ++j) ACC4(g2h[ntl_u32(esrc + s + j)])
    float h0 = fmaxf(fmaf(a0, dv, b2[0]), 0.f);
    float h1 = fmaxf(fmaf(a1, dv, b2[1]), 0.f);
    float h2 = fmaxf(fmaf(a2, dv, b2[2]), 0.f);
    float h3 = fmaxf(fmaf(a3, dv, b2[3]), 0.f);
    float o0 = dv * (h0 * W3[0] + h1 * W3[2] + h2 * W3[4] + h3 * W3[6]);
    float o1 = dv * (h0 * W3[1] + h1 * W3[3] + h2 * W3[5] + h3 * W3[7]);
    __half2 oo = __floats2half2_rn(o0, o1);
    g3h[i] = *(unsigned*)&oo;
}

__device__ __forceinline__ void phase3(int i, int lo, int hi, int cs, int s,
        const unsigned* se, const unsigned* __restrict__ esrc,
        const unsigned* __restrict__ g3h, float dv,
        const float* __restrict__ b3, const float* __restrict__ Wl,
        const float* __restrict__ bl, float* __restrict__ out, int N) {
    unsigned pk = g3h[i];
    float2 v = __half22float2(*(__half2*)&pk);
    float ax = v.x, ay = v.y;
    int hi2 = min(hi, cs);
    int j = lo;
    for (; j + 8 <= hi2; j += 8) {
        unsigned q0 = g3h[se[j]],   q1 = g3h[se[j+1]], q2 = g3h[se[j+2]], q3 = g3h[se[j+3]];
        unsigned q4 = g3h[se[j+4]], q5 = g3h[se[j+5]], q6 = g3h[se[j+6]], q7 = g3h[se[j+7]];
        float2 v0 = __half22float2(*(__half2*)&q0);
        float2 v1 = __half22float2(*(__half2*)&q1);
        float2 v2 = __half22float2(*(__half2*)&q2);
        float2 v3 = __half22float2(*(__half2*)&q3);
        float2 v4 = __half22float2(*(__half2*)&q4);
        float2 v5 = __half22float2(*(__half2*)&q5);
        float2 v6 = __half22float2(*(__half2*)&q6);
        float2 v7 = __half22float2(*(__half2*)&q7);
        ax += (v0.x + v1.x + v2.x + v3.x) + (v4.x + v5.x + v6.x + v7.x);
        ay += (v0.y + v1.y + v2.y + v3.y) + (v4.y + v5.y + v6.y + v7.y);
    }
    for (; j + 4 <= hi2; j += 4) {
        unsigned q0 = g3h[se[j]], q1 = g3h[se[j+1]], q2 = g3h[se[j+2]], q3 = g3h[se[j+3]];
        float2 v0 = __half22float2(*(__half2*)&q0);
        float2 v1 = __half22float2(*(__half2*)&q1);
        float2 v2 = __half22float2(*(__half2*)&q2);
        float2 v3 = __half22float2(*(__half2*)&q3);
        ax += v0.x + v1.x + v2.x + v3.x;
        ay += v0.y + v1.y + v2.y + v3.y;
    }
    for (; j < hi2; ++j) {
        unsigned q = g3h[se[j]];
        float2 w = __half22float2(*(__half2*)&q);
        ax += w.x; ay += w.y;
    }
    for (; j < hi; ++j) {
        unsigned q = g3h[ntl_u32(esrc + s + j)];
        float2 w = __half22float2(*(__half2*)&q);
        ax += w.x; ay += w.y;
    }
    float h0 = fmaxf(fmaf(ax, dv, b3[0]), 0.f);
    float h1 = fmaxf(fmaf(ay, dv, b3[1]), 0.f);
    v4f oo;
    oo.x = fmaf(h0, Wl[0], fmaf(h1, Wl[4], bl[0]));
    oo.y = fmaf(h0, Wl[1], fmaf(h1, Wl[5], bl[1]));
    oo.z = fmaf(h0, Wl[2], fmaf(h1, Wl[6], bl[2]));
    oo.w = fmaf(h0, Wl[3], fmaf(h1, Wl[7], bl[3]));
    __builtin_nontemporal_store(oo, (v4f*)out + i);
    v2f h; h.x = h0; h.y = h1;
    __builtin_nontemporal_store(h, (v2f*)(out + (size_t)4 * N) + i);
}

// common per-block geometry
struct BlkGeo { int s, cs, lo, hi; bool act; int i; float dv; };

__device__ __forceinline__ BlkGeo geo(const int* __restrict__ nodeoff,
                                      const int* __restrict__ bend,
                                      const float* __restrict__ dinv, int N) {
    BlkGeo g;
    int t = threadIdx.x, blk = blockIdx.x, buk = blk >> 1;
    int gbase = (buk << BUCKET_BITS) + ((blk & 1) << 8);
    int nn = min(256, N - gbase);
    g.i = gbase + t;
    g.act = (nn > 0) && (t < nn);
    g.s = 0; g.cs = 0; g.lo = 0; g.hi = 0; g.dv = 0.f;
    if (nn > 0) {
        g.s = nodeoff[gbase];
        int nbn = min(512, N - (buk << BUCKET_BITS));
        bool lasthalf = (blk & 1) ? true : (nbn <= 256);
        int e = lasthalf ? bend[buk] : nodeoff[gbase + 256];
        g.cs = min(e - g.s, SMAX_A);
        if (g.act) {
            bool lastnode = lasthalf && (t == nn - 1);
            g.lo = nodeoff[g.i] - g.s;
            g.hi = (lastnode ? bend[buk] : nodeoff[g.i + 1]) - g.s;
            g.dv = dinv[g.i];
        }
    }
    return g;
}

// --- kernel 3 (cooperative): all three agg layers, edge slice staged once ---
__global__ void __launch_bounds__(AGG_BLK, 8)
aggf_kernel(const unsigned* __restrict__ esrc, const int* __restrict__ nodeoff,
            const int* __restrict__ bend, const float* __restrict__ dinv,
            uint2* __restrict__ g1h, uint2* __restrict__ g2h,
            const float* __restrict__ b1, const float* __restrict__ W2,
            const float* __restrict__ b2, const float* __restrict__ W3,
            const float* __restrict__ b3, const float* __restrict__ Wl,
            const float* __restrict__ bl, float* __restrict__ out, int N) {
    cg::grid_group gg = cg::this_grid();
    __shared__ unsigned se[SMAX_A];
    BlkGeo g = geo(nodeoff, bend, dinv, N);
    int t = threadIdx.x;
    for (int j = t; j < g.cs; j += AGG_BLK) se[j] = ntl_u32(esrc + g.s + j);
    __syncthreads();
    if (g.act) phase1(g.i, g.lo, g.hi, g.cs, g.s, se, esrc, g1h, g.dv, b1, W2, g2h);
    gg.sync();
    unsigned* g3h = (unsigned*)g1h;  // g1 dead after phase1
    if (g.act) phase2(g.i, g.lo, g.hi, g.cs, g.s, se, esrc, g2h, g.dv, b2, W3, g3h);
    gg.sync();
    if (g.act) phase3(g.i, g.lo, g.hi, g.cs, g.s, se, esrc, g3h, g.dv, b3, Wl, bl, out, N);
}

// --- fallback: one phase per launch (if cooperative capacity insufficient) ---
template <int P>
__global__ void __launch_bounds__(AGG_BLK)
aggp_kernel(const unsigned* __restrict__ esrc, const int* __restrict__ nodeoff,
            const int* __restrict__ bend, const float* __restrict__ dinv,
            uint2* __restrict__ g1h, uint2* __restrict__ g2h,
            const float* __restrict__ b1, const float* __restrict__ W2,
            const float* __restrict__ b2, const float* __restrict__ W3,
            const float* __restrict__ b3, const float* __restrict__ Wl,
            const float* __restrict__ bl, float* __restrict__ out, int N) {
    __shared__ unsigned se[SMAX_A];
    BlkGeo g = geo(nodeoff, bend, dinv, N);
    int t = threadIdx.x;
    for (int j = t; j < g.cs; j += AGG_BLK) se[j] = ntl_u32(esrc + g.s + j);
    __syncthreads();
    unsigned* g3h = (unsigned*)g1h;
    if (g.act) {
        if (P == 1) phase1(g.i, g.lo, g.hi, g.cs, g.s, se, esrc, g1h, g.dv, b1, W2, g2h);
        if (P == 2) phase2(g.i, g.lo, g.hi, g.cs, g.s, se, esrc, g2h, g.dv, b2, W3, g3h);
        if (P == 3) phase3(g.i, g.lo, g.hi, g.cs, g.s, se, esrc, g3h, g.dv, b3, Wl, bl, out, N);
    }
}

extern "C" void kernel_launch(void* const* d_in, const int* in_sizes, int n_in,
                              void* d_out, int out_size, void* d_ws, size_t ws_size,
                              hipStream_t stream) {
    const float* x  = (const float*)d_in[0];
    const int*   ei = (const int*)d_in[1];
    const float* W1 = (const float*)d_in[2];
    const float* b1 = (const float*)d_in[3];
    const float* W2 = (const float*)d_in[4];
    const float* b2 = (const float*)d_in[5];
    const float* W3 = (const float*)d_in[6];
    const float* b3 = (const float*)d_in[7];
    const float* Wl = (const float*)d_in[8];
    const float* bl = (const float*)d_in[9];
    float* out = (float*)d_out;

    int N = in_sizes[0] / 34;
    const int E = in_sizes[1] / 2;
    const int* src = ei;
    const int* dst = ei + E;
    const int NBUK = (N + BUCKET - 1) >> BUCKET_BITS;

    auto al16 = [](size_t v) { return (v + 15) & ~(size_t)15; };
    char* w = (char*)d_ws;
    size_t off = 0;
    int*      gcur    = (int*)(w + off);      off += al16((size_t)NBUK * PAD * 4);
    int*      bend    = (int*)(w + off);      off += al16((size_t)NBUK * 4);
    float*    dinv    = (float*)(w + off);    off += al16((size_t)N * 4);
    int*      nodeoff = (int*)(w + off);      off += al16((size_t)(N + 1) * 4);
    unsigned* ep      = (unsigned*)(w + off); off += al16((size_t)NBUK * REGION * 4);
    uint2*    g1h     = (uint2*)(w + off);    off += al16((size_t)(N + 1) * 8);
    uint2*    g2h     = (uint2*)(w + off);

    const int nb_bin = (E + BIN_CHUNK - 1) / BIN_CHUNK;
    const int nb_agg = 2 * NBUK;

    init_kernel<<<(NBUK + 255) / 256, 256, 0, stream>>>(gcur, NBUK);
    bin_kernel<<<nb_bin, BIN_BLK, 0, stream>>>(src, dst, gcur, ep, E, NBUK);
    sortb_kernel<<<NBUK, SB_BLK, 0, stream>>>(ep, gcur, x, W1, dinv, nodeoff, bend, g1h, N, NBUK);

    // cooperative fused agg if all blocks fit concurrently, else 3 launches
    int blocksPerCU = 0, ncu = 0, dev = 0;
    hipGetDevice(&dev);
    hipDeviceGetAttribute(&ncu, hipDeviceAttributeMultiprocessorCount, dev);
    hipOccupancyMaxActiveBlocksPerMultiprocessor(&blocksPerCU, (const void*)aggf_kernel, AGG_BLK, 0);
    if (blocksPerCU * ncu >= nb_agg) {
        void* args[] = {(void*)&ep, (void*)&nodeoff, (void*)&bend, (void*)&dinv,
                        (void*)&g1h, (void*)&g2h, (void*)&b1, (void*)&W2,
                        (void*)&b2, (void*)&W3, (void*)&b3, (void*)&Wl,
                        (void*)&bl, (void*)&out, (void*)&N};
        hipLaunchCooperativeKernel((const void*)aggf_kernel, dim3(nb_agg), dim3(AGG_BLK),
                                   args, 0, stream);
    } else {
        aggp_kernel<1><<<nb_agg, AGG_BLK, 0, stream>>>(ep, nodeoff, bend, dinv, g1h, g2h,
                                                       b1, W2, b2, W3, b3, Wl, bl, out, N);
        aggp_kernel<2><<<nb_agg, AGG_BLK, 0, stream>>>(ep, nodeoff, bend, dinv, g1h, g2h,
                                                       b1, W2, b2, W3, b3, Wl, bl, out, N);
        aggp_kernel<3><<<nb_agg, AGG_BLK, 0, stream>>>(ep, nodeoff, bend, dinv, g1h, g2h,
                                                       b1, W2, b2, W3, b3, Wl, bl, out, N);
    }
}